// Round 7
// baseline (351.673 us; speedup 1.0000x reference)
//
#include <hip/hip_runtime.h>
#include <hip/hip_bf16.h>
#include <hip/hip_cooperative_groups.h>
#include <stdint.h>

namespace cg = cooperative_groups;

#define HEAD 64
#define CEMB 1024
#define BB 8
#define TSEQ 2048

typedef __attribute__((ext_vector_type(8))) short bf16x8;
typedef __attribute__((ext_vector_type(4))) float f32x4;

__device__ __forceinline__ unsigned short f2bf(float f) {
    union { float f; uint32_t u; } c; c.f = f;
    uint32_t u = c.u + 0x7FFF + ((c.u >> 16) & 1);
    return (unsigned short)(u >> 16);
}
__device__ __forceinline__ ushort4 f4bf(float4 v) {
    ushort4 u; u.x = f2bf(v.x); u.y = f2bf(v.y); u.z = f2bf(v.z); u.w = f2bf(v.w);
    return u;
}

// Single fused cooperative kernel: 256 blocks x 768 threads (12 waves, 1 blk/CU).
// Phase 0 (blocks 0-31): W -> WTf MFMA-fragment order.   grid.sync()
// Phase 1: proj GEMM, register-resident B (half-K).       grid.sync()
// Phase 2: causal softplus-attention, 2 balanced jobs/block, 12-way s-split.
__global__ __launch_bounds__(768) void fused_attn(
        const float* __restrict__ x,
        const float* __restrict__ Wk, const float* __restrict__ bk,
        const float* __restrict__ Wq, const float* __restrict__ bq,
        const float* __restrict__ Wv, const float* __restrict__ bv,
        unsigned short* __restrict__ WTf, float* __restrict__ biasb,
        unsigned short* __restrict__ Kb, unsigned short* __restrict__ Qb,
        unsigned short* __restrict__ VTb, float* __restrict__ out) {
    __shared__ __align__(16) char smem[132096];   // proj As 129KB; attn Pl+red 84KB

    cg::grid_group grid = cg::this_grid();
    const int tid = threadIdx.x;
    const int lane = tid & 63, w = tid >> 6;      // 12 waves
    const int l15 = lane & 15, q4 = lane >> 4;
    const int g = blockIdx.x;

    // ================= Phase 0: prep W fragments (blocks 0-31) =================
    {
        float* Wl = (float*)smem;                 // [3][32][64]
        if (g < 32 && tid < 256) {
            const int kc = g;
            const float* Ws[3] = {Wk, Wq, Wv};
            const int row = tid >> 3, cf = (tid & 7) * 8;
            #pragma unroll
            for (int p = 0; p < 3; p++) {
                const float* W = Ws[p] + (long)(kc * 32 + row) * 64 + cf;
                float4 v0 = *(const float4*)(W);
                float4 v1 = *(const float4*)(W + 4);
                *(float4*)(Wl + ((p * 32 + row) * 64 + cf)) = v0;
                *(float4*)(Wl + ((p * 32 + row) * 64 + cf + 4)) = v1;
            }
        }
        __syncthreads();
        if (g < 32 && tid < 256) {
            const int kc = g;
            #pragma unroll
            for (int i = 0; i < 3; i++) {
                int cid = i * 256 + tid;          // 0..767 = j*64 + lane
                int ln = cid & 63;
                int li = ln & 15, qq = ln >> 4;
                int n = (cid >> 6) * 16 + li;
                int p = n >> 6, col = n & 63;
                float scale = (p == 1) ? 0.03125f : 1.0f;   // fold C^-0.5 into q
                unsigned short o[8];
                for (int e = 0; e < 8; e++)
                    o[e] = f2bf(Wl[(p * 32 + qq * 8 + e) * 64 + col] * scale);
                *(int4*)(WTf + (long)kc * 6144 + (long)cid * 8) = *(int4*)o;
            }
            if (kc == 0 && tid < 192) {
                const float* bs[3] = {bk, bq, bv};
                int p = tid >> 6;
                biasb[tid] = bs[p][tid & 63] * ((p == 1) ? 0.03125f : 1.0f);
            }
        }
    }
    __threadfence();
    grid.sync();

    // ================= Phase 1: proj GEMM (R6 structure) =======================
    {
        unsigned short* As = (unsigned short*)smem;   // [64][1032]
        const long rowbase = (long)g * 64;
        const float* xg = x + rowbase * CEMB;
        const unsigned short* Bg = WTf + w * 512 + (long)lane * 8;

        f32x4 z = {0.f, 0.f, 0.f, 0.f};
        f32x4 acc[4];
        #pragma unroll
        for (int m = 0; m < 4; m++) acc[m] = z;

        bf16x8 Breg[16];

        // stage segment 0 (rows x k[0:128])
        #pragma unroll
        for (int it = 0; it < 3; it++) {
            int i = it * 768 + tid;
            if (i < 2048) {
                int row = i >> 5, c4 = (i & 31) * 4;
                float4 v = *(const float4*)(xg + row * CEMB + c4);
                *(ushort4*)(As + row * 1032 + c4) = f4bf(v);
            }
        }
        __syncthreads();

        #pragma unroll
        for (int half = 0; half < 2; half++) {
            #pragma unroll
            for (int i = 0; i < 16; i++)
                Breg[i] = *(const bf16x8*)(Bg + (long)(half * 16 + i) * 6144);

            #pragma unroll
            for (int ss = 0; ss < 4; ss++) {
                const int s = half * 4 + ss;
                float4 pf[3];
                if (s < 7) {
                    #pragma unroll
                    for (int it = 0; it < 3; it++) {
                        int i = it * 768 + tid;
                        if (i < 2048) {
                            int row = i >> 5, c4 = (i & 31) * 4;
                            pf[it] = *(const float4*)(xg + row * CEMB + (s + 1) * 128 + c4);
                        }
                    }
                }
                #pragma unroll
                for (int kc = 0; kc < 4; kc++) {
                    const int kg = s * 4 + kc;
                    #pragma unroll
                    for (int m = 0; m < 4; m++) {
                        bf16x8 a = *(const bf16x8*)(As + (m * 16 + l15) * 1032 + kg * 32 + q4 * 8);
                        acc[m] = __builtin_amdgcn_mfma_f32_16x16x32_bf16(a, Breg[ss * 4 + kc], acc[m], 0, 0, 0);
                    }
                }
                if (s < 7) {
                    #pragma unroll
                    for (int it = 0; it < 3; it++) {
                        int i = it * 768 + tid;
                        if (i < 2048) {
                            int row = i >> 5, c4 = (i & 31) * 4;
                            *(ushort4*)(As + row * 1032 + (s + 1) * 128 + c4) = f4bf(pf[it]);
                        }
                    }
                    __syncthreads();
                }
            }
        }

        // epilogue: +bias, cast bf16, per-wave scatter
        const int n = w * 16 + l15;
        const float bias = biasb[n];
        #pragma unroll
        for (int m = 0; m < 4; m++) {
            const long row0 = rowbase + m * 16 + q4 * 4;
            if (n < 128) {
                unsigned short* dst = (n < 64) ? (Kb + row0 * HEAD + n)
                                               : (Qb + row0 * HEAD + (n - 64));
                for (int r = 0; r < 4; r++)
                    dst[r * HEAD] = f2bf(acc[m][r] + bias);
            } else {
                const int h = n - 128;
                const long b = row0 >> 11; const int t = (int)(row0 & 2047);
                ushort4 pk;
                pk.x = f2bf(acc[m][0] + bias);
                pk.y = f2bf(acc[m][1] + bias);
                pk.z = f2bf(acc[m][2] + bias);
                pk.w = f2bf(acc[m][3] + bias);
                *(ushort4*)(VTb + b * (HEAD * (long)TSEQ) + (long)h * TSEQ + t) = pk;
            }
        }
    }
    __threadfence();
    grid.sync();

    // ================= Phase 2: attention, 2 balanced jobs/block ===============
    {
        unsigned short* Pl = (unsigned short*)smem;        // 12 x 1280 shorts (30720 B)
        float* red = (float*)(smem + 30720);               // 6 slots x 64 x 36 floats
        unsigned short* myP = Pl + w * 1280;

        #pragma unroll 1
        for (int jj = 0; jj < 2; jj++) {
            const int j = jj ? (511 - g) : g;
            const int ti = 63 - (j >> 3);                  // t-tile 0..63
            const int b = j & 7;
            const int t0 = ti * 32;

            const unsigned short* kb  = Kb  + (long)b * TSEQ * HEAD;
            const unsigned short* qb  = Qb  + (long)b * TSEQ * HEAD;
            const unsigned short* vtb = VTb + (long)b * HEAD * TSEQ;

            bf16x8 kf[2][2];
            for (int tt = 0; tt < 2; tt++)
                for (int kk = 0; kk < 2; kk++)
                    kf[tt][kk] = *(const bf16x8*)(kb + (t0 + tt * 16 + l15) * HEAD + kk * 32 + q4 * 8);

            f32x4 z = {0.f, 0.f, 0.f, 0.f};
            f32x4 oacc[4][2];
            for (int hh = 0; hh < 4; hh++) for (int tt = 0; tt < 2; tt++) oacc[hh][tt] = z;

            bf16x8 qpf[2][2], vpf[4];
            if (w <= ti) {
                const int s0 = w * 32;
                for (int st2 = 0; st2 < 2; st2++)
                    for (int kk = 0; kk < 2; kk++)
                        qpf[st2][kk] = *(const bf16x8*)(qb + (s0 + st2 * 16 + l15) * HEAD + kk * 32 + q4 * 8);
                for (int hh = 0; hh < 4; hh++)
                    vpf[hh] = *(const bf16x8*)(vtb + (hh * 16 + l15) * (long)TSEQ + s0 + q4 * 8);
            }

            for (int c = w; c <= ti; c += 12) {
                const int s0 = c * 32;
                bf16x8 qf[2][2], vf[4];
                for (int st2 = 0; st2 < 2; st2++)
                    for (int kk = 0; kk < 2; kk++) qf[st2][kk] = qpf[st2][kk];
                for (int hh = 0; hh < 4; hh++) vf[hh] = vpf[hh];

                if (c + 12 <= ti) {
                    const int sn = (c + 12) * 32;
                    for (int st2 = 0; st2 < 2; st2++)
                        for (int kk = 0; kk < 2; kk++)
                            qpf[st2][kk] = *(const bf16x8*)(qb + (sn + st2 * 16 + l15) * HEAD + kk * 32 + q4 * 8);
                    for (int hh = 0; hh < 4; hh++)
                        vpf[hh] = *(const bf16x8*)(vtb + (hh * 16 + l15) * (long)TSEQ + sn + q4 * 8);
                }

                f32x4 sc[2][2];
                for (int st2 = 0; st2 < 2; st2++)
                    for (int tt = 0; tt < 2; tt++) {
                        f32x4 s = z;
                        s = __builtin_amdgcn_mfma_f32_16x16x32_bf16(qf[st2][0], kf[tt][0], s, 0, 0, 0);
                        s = __builtin_amdgcn_mfma_f32_16x16x32_bf16(qf[st2][1], kf[tt][1], s, 0, 0, 0);
                        sc[st2][tt] = s;
                    }
                for (int tt = 0; tt < 2; tt++) {
                    const int tg = t0 + tt * 16 + l15;
                    for (int st2 = 0; st2 < 2; st2++) {
                        ushort4 pk;
                        unsigned short pv[4];
                        for (int r = 0; r < 4; r++) {
                            int sg = s0 + st2 * 16 + q4 * 4 + r;
                            float p = __logf(1.0f + __expf(sc[st2][tt][r]));
                            if (sg > tg) p = 0.0f;
                            pv[r] = f2bf(p);
                        }
                        pk.x = pv[0]; pk.y = pv[1]; pk.z = pv[2]; pk.w = pv[3];
                        *(ushort4*)(myP + (tt * 16 + l15) * 40 + st2 * 16 + q4 * 4) = pk;
                    }
                }
                __threadfence_block();
                bf16x8 pf0 = *(const bf16x8*)(myP + l15 * 40 + q4 * 8);
                bf16x8 pf1 = *(const bf16x8*)(myP + (16 + l15) * 40 + q4 * 8);
                for (int hh = 0; hh < 4; hh++) {
                    oacc[hh][0] = __builtin_amdgcn_mfma_f32_16x16x32_bf16(vf[hh], pf0, oacc[hh][0], 0, 0, 0);
                    oacc[hh][1] = __builtin_amdgcn_mfma_f32_16x16x32_bf16(vf[hh], pf1, oacc[hh][1], 0, 0, 0);
                }
            }

            // ---- tree reduction over 12 waves: 12 -> 6 -> 3 -> 1 ----
            __syncthreads();                     // S0: red region free
            if (w >= 6) {
                float* r0 = red + (w - 6) * 2304 + lane * 36;
                for (int hh = 0; hh < 4; hh++)
                    for (int tt = 0; tt < 2; tt++)
                        *(f32x4*)(r0 + (hh * 2 + tt) * 4) = oacc[hh][tt];
            }
            __syncthreads();                     // S1
            if (w < 6) {
                const float* r0 = red + w * 2304 + lane * 36;
                for (int hh = 0; hh < 4; hh++)
                    for (int tt = 0; tt < 2; tt++)
                        oacc[hh][tt] += *(const f32x4*)(r0 + (hh * 2 + tt) * 4);
            }
            __syncthreads();                     // S2
            if (w >= 3 && w < 6) {
                float* r0 = red + (w - 3) * 2304 + lane * 36;
                for (int hh = 0; hh < 4; hh++)
                    for (int tt = 0; tt < 2; tt++)
                        *(f32x4*)(r0 + (hh * 2 + tt) * 4) = oacc[hh][tt];
            }
            __syncthreads();                     // S3
            if (w < 3) {
                const float* r0 = red + w * 2304 + lane * 36;
                for (int hh = 0; hh < 4; hh++)
                    for (int tt = 0; tt < 2; tt++)
                        oacc[hh][tt] += *(const f32x4*)(r0 + (hh * 2 + tt) * 4);
            }
            __syncthreads();                     // S4
            if (w == 1 || w == 2) {
                float* r0 = red + (w - 1) * 2304 + lane * 36;
                for (int hh = 0; hh < 4; hh++)
                    for (int tt = 0; tt < 2; tt++)
                        *(f32x4*)(r0 + (hh * 2 + tt) * 4) = oacc[hh][tt];
            }
            __syncthreads();                     // S5
            if (w == 0) {
                for (int i = 0; i < 2; i++) {
                    const float* r0 = red + i * 2304 + lane * 36;
                    for (int hh = 0; hh < 4; hh++)
                        for (int tt = 0; tt < 2; tt++)
                            oacc[hh][tt] += *(const f32x4*)(r0 + (hh * 2 + tt) * 4);
                }
                for (int tt = 0; tt < 2; tt++) {
                    float* ob = out + ((long)b * TSEQ + t0 + tt * 16 + l15) * HEAD + q4 * 4;
                    for (int hh = 0; hh < 4; hh++)
                        *(f32x4*)(ob + hh * 16) = oacc[hh][tt];
                }
            }
        }
    }
}

// ---------------- host launch ------------------------------------------------
extern "C" void kernel_launch(void* const* d_in, const int* in_sizes, int n_in,
                              void* d_out, int out_size, void* d_ws, size_t ws_size,
                              hipStream_t stream) {
    const float* x  = (const float*)d_in[0];
    const float* Wk = (const float*)d_in[1];
    const float* bk = (const float*)d_in[2];
    const float* Wq = (const float*)d_in[3];
    const float* bq = (const float*)d_in[4];
    const float* Wv = (const float*)d_in[5];
    const float* bv = (const float*)d_in[6];
    float* out = (float*)d_out;

    char* ws = (char*)d_ws;
    unsigned short* WTf   = (unsigned short*)(ws);                      // 384 KB
    float*          biasb = (float*)(ws + 393216);                      // 768 B
    unsigned short* Kb    = (unsigned short*)(ws + 524288);             // 2 MB
    unsigned short* Qb    = (unsigned short*)(ws + 524288 + 2097152);   // 2 MB
    unsigned short* VTb   = (unsigned short*)(ws + 524288 + 4194304);   // 2 MB

    void* args[] = {(void*)&x, (void*)&Wk, (void*)&bk, (void*)&Wq, (void*)&bq,
                    (void*)&Wv, (void*)&bv, (void*)&WTf, (void*)&biasb,
                    (void*)&Kb, (void*)&Qb, (void*)&VTb, (void*)&out};
    hipLaunchCooperativeKernel((const void*)fused_attn, dim3(256), dim3(768),
                               args, 0, stream);
}

// Round 8
// 178.261 us; speedup vs baseline: 1.9728x; 1.9728x over previous
//
#include <hip/hip_runtime.h>
#include <hip/hip_bf16.h>
#include <stdint.h>

#define HEAD 64
#define CEMB 1024
#define BB 8
#define TSEQ 2048

typedef __attribute__((ext_vector_type(8))) short bf16x8;
typedef __attribute__((ext_vector_type(4))) float f32x4;

__device__ __forceinline__ unsigned short f2bf(float f) {
    union { float f; uint32_t u; } c; c.f = f;
    uint32_t u = c.u + 0x7FFF + ((c.u >> 16) & 1);
    return (unsigned short)(u >> 16);
}
__device__ __forceinline__ ushort4 f4bf(float4 v) {
    ushort4 u; u.x = f2bf(v.x); u.y = f2bf(v.y); u.z = f2bf(v.z); u.w = f2bf(v.w);
    return u;
}

// ---------------- Kernel 0: W -> WTf, MFMA-fragment order --------------------
// Fragment (kc, j): 64 lanes x 16B contiguous (1 KB); n = j*16+(lane&15),
// k = kc*32 + (lane>>4)*8 + e.  j: 0-3 K, 4-7 Q(scaled), 8-11 V.
__global__ __launch_bounds__(256) void prep_w(
        const float* __restrict__ Wk, const float* __restrict__ bk,
        const float* __restrict__ Wq, const float* __restrict__ bq,
        const float* __restrict__ Wv, const float* __restrict__ bv,
        unsigned short* __restrict__ WTf, float* __restrict__ biasb) {
    __shared__ float Wl[3][32][64];
    const int kc = blockIdx.x;               // 0..31
    const int tid = threadIdx.x;
    const float* Ws[3] = {Wk, Wq, Wv};
    const int row = tid >> 3, cf = (tid & 7) * 8;
    #pragma unroll
    for (int p = 0; p < 3; p++) {
        const float* W = Ws[p] + (long)(kc * 32 + row) * 64 + cf;
        float4 v0 = *(const float4*)(W);
        float4 v1 = *(const float4*)(W + 4);
        *(float4*)(&Wl[p][row][cf]) = v0;
        *(float4*)(&Wl[p][row][cf + 4]) = v1;
    }
    __syncthreads();
    #pragma unroll
    for (int i = 0; i < 3; i++) {
        int cid = i * 256 + tid;             // 0..767 = j*64 + lane
        int lane = cid & 63;
        int l15 = lane & 15, q4 = lane >> 4;
        int n = (cid >> 6) * 16 + l15;
        int p = n >> 6, col = n & 63;
        float scale = (p == 1) ? 0.03125f : 1.0f;   // fold C^-0.5 into q
        unsigned short o[8];
        for (int e = 0; e < 8; e++) o[e] = f2bf(Wl[p][q4 * 8 + e][col] * scale);
        *(int4*)(WTf + (long)kc * 6144 + (long)cid * 8) = *(int4*)o;
    }
    if (kc == 0 && tid < 192) {
        const float* bs[3] = {bk, bq, bv};
        int p = tid >> 6;
        biasb[tid] = bs[p][tid & 63] * ((p == 1) ? 0.03125f : 1.0f);
    }
}

// ---------------- Kernel 1: projections, register-resident B (quarter-K) -----
// grid 256 x 768thr (12 waves, 1 blk/CU). __launch_bounds__(768,3): 3 waves/EU
// -> 170-VGPR cap. R5-R7 used the default, which capped ~80 and SPILLED the
// B-stripe (R7 counter: VGPR_Count=80 vs 120 needed). Breg[8]=32 VGPRs held
// per K-quarter; each fragment still loaded exactly once per CU (L2-hot).
__global__ __launch_bounds__(768, 3) void proj_gemm(
        const float* __restrict__ x, const unsigned short* __restrict__ WTf,
        const float* __restrict__ biasb,
        unsigned short* __restrict__ Kb, unsigned short* __restrict__ Qb,
        unsigned short* __restrict__ VTb) {
    __shared__ __align__(16) unsigned short As[64 * 1032];   // 132 KB

    const int tid = threadIdx.x;
    const int lane = tid & 63, w = tid >> 6;     // w = n-tile 0..11
    const int l15 = lane & 15, q4 = lane >> 4;
    const long rowbase = (long)blockIdx.x * 64;
    const float* xg = x + rowbase * CEMB;
    const unsigned short* Bg = WTf + w * 512 + (long)lane * 8;

    f32x4 z = {0.f, 0.f, 0.f, 0.f};
    f32x4 acc[4];
    #pragma unroll
    for (int m = 0; m < 4; m++) acc[m] = z;

    bf16x8 Breg[8];

    // ---- stage segment 0 (rows x k[0:128]) ----
    #pragma unroll
    for (int it = 0; it < 3; it++) {
        int i = it * 768 + tid;
        if (i < 2048) {
            int row = i >> 5, c4 = (i & 31) * 4;
            float4 v = *(const float4*)(xg + row * CEMB + c4);
            *(ushort4*)(As + row * 1032 + c4) = f4bf(v);
        }
    }
    __syncthreads();

    // ---- pipelined K-loop: 4 quarters x 2 segments ----
    #pragma unroll
    for (int qtr = 0; qtr < 4; qtr++) {
        // load this quarter's 8 B-fragments (32 VGPRs; coalesced 1KB, L2-hot)
        #pragma unroll
        for (int i = 0; i < 8; i++)
            Breg[i] = *(const bf16x8*)(Bg + (long)(qtr * 8 + i) * 6144);

        #pragma unroll
        for (int ss = 0; ss < 2; ss++) {
            const int s = qtr * 2 + ss;
            float4 pf[3];
            // issue seg s+1 global loads (in flight across MFMA below)
            if (s < 7) {
                #pragma unroll
                for (int it = 0; it < 3; it++) {
                    int i = it * 768 + tid;
                    if (i < 2048) {
                        int row = i >> 5, c4 = (i & 31) * 4;
                        pf[it] = *(const float4*)(xg + row * CEMB + (s + 1) * 128 + c4);
                    }
                }
            }
            // compute seg s: 4 kc x 4 m-tiles, B from registers
            #pragma unroll
            for (int kc = 0; kc < 4; kc++) {
                const int kg = s * 4 + kc;
                #pragma unroll
                for (int m = 0; m < 4; m++) {
                    bf16x8 a = *(const bf16x8*)(As + (m * 16 + l15) * 1032 + kg * 32 + q4 * 8);
                    acc[m] = __builtin_amdgcn_mfma_f32_16x16x32_bf16(a, Breg[ss * 4 + kc], acc[m], 0, 0, 0);
                }
            }
            // store seg s+1 (disjoint LDS region), then barrier
            if (s < 7) {
                #pragma unroll
                for (int it = 0; it < 3; it++) {
                    int i = it * 768 + tid;
                    if (i < 2048) {
                        int row = i >> 5, c4 = (i & 31) * 4;
                        *(ushort4*)(As + row * 1032 + (s + 1) * 128 + c4) = f4bf(pf[it]);
                    }
                }
                __syncthreads();
            }
        }
    }

    // ---- epilogue: +bias, cast bf16, per-wave scatter ----
    const int n = w * 16 + l15;
    const float bias = biasb[n];
    #pragma unroll
    for (int m = 0; m < 4; m++) {
        const long row0 = rowbase + m * 16 + q4 * 4;
        if (n < 128) {
            unsigned short* dst = (n < 64) ? (Kb + row0 * HEAD + n)
                                           : (Qb + row0 * HEAD + (n - 64));
            for (int r = 0; r < 4; r++)
                dst[r * HEAD] = f2bf(acc[m][r] + bias);
        } else {
            const int h = n - 128;
            const long b = row0 >> 11; const int t = (int)(row0 & 2047);
            ushort4 pk;
            pk.x = f2bf(acc[m][0] + bias);
            pk.y = f2bf(acc[m][1] + bias);
            pk.z = f2bf(acc[m][2] + bias);
            pk.w = f2bf(acc[m][3] + bias);
            *(ushort4*)(VTb + b * (HEAD * (long)TSEQ) + (long)h * TSEQ + t) = pk;
        }
    }
}

// ---------------- Kernel 2: causal softplus-attention, 8 waves ---------------
// grid 512 x 512thr. __launch_bounds__(512,4): 4 waves/EU -> 128-VGPR cap for
// the ~110-reg working set (default capped ~80 and spilled). 2 blocks/CU.
__global__ __launch_bounds__(512, 4) void attn(
        const unsigned short* __restrict__ Kb, const unsigned short* __restrict__ Qb,
        const unsigned short* __restrict__ VTb, float* __restrict__ out) {
    __shared__ __align__(16) char sm[36864];   // union: Pl 20480 | red 36864
    unsigned short* Pl = (unsigned short*)sm;  // [8 waves][32*40]
    float* red = (float*)sm;                   // [4][64*36]

    const int tid = threadIdx.x;
    const int lane = tid & 63, w = tid >> 6;   // 8 waves
    const int l15 = lane & 15, q4 = lane >> 4;

    const int bid = blockIdx.x;
    const int ti = 63 - (bid >> 3);            // largest t-tile first
    const int b = bid & 7;
    const int t0 = ti * 32;

    const unsigned short* kb  = Kb  + (long)b * TSEQ * HEAD;
    const unsigned short* qb  = Qb  + (long)b * TSEQ * HEAD;
    const unsigned short* vtb = VTb + (long)b * HEAD * TSEQ;

    bf16x8 kf[2][2];
    for (int tt = 0; tt < 2; tt++)
        for (int kk = 0; kk < 2; kk++)
            kf[tt][kk] = *(const bf16x8*)(kb + (t0 + tt * 16 + l15) * HEAD + kk * 32 + q4 * 8);

    f32x4 z = {0.f, 0.f, 0.f, 0.f};
    f32x4 oacc[4][2];
    for (int hh = 0; hh < 4; hh++) for (int tt = 0; tt < 2; tt++) oacc[hh][tt] = z;

    bf16x8 qpf[2][2], vpf[4];
    if (w <= ti) {
        const int s0 = w * 32;
        for (int st2 = 0; st2 < 2; st2++)
            for (int kk = 0; kk < 2; kk++)
                qpf[st2][kk] = *(const bf16x8*)(qb + (s0 + st2 * 16 + l15) * HEAD + kk * 32 + q4 * 8);
        for (int hh = 0; hh < 4; hh++)
            vpf[hh] = *(const bf16x8*)(vtb + (hh * 16 + l15) * (long)TSEQ + s0 + q4 * 8);
    }

    unsigned short* myP = Pl + w * 1280;
    for (int c = w; c <= ti; c += 8) {
        const int s0 = c * 32;

        bf16x8 qf[2][2], vf[4];
        for (int st2 = 0; st2 < 2; st2++)
            for (int kk = 0; kk < 2; kk++) qf[st2][kk] = qpf[st2][kk];
        for (int hh = 0; hh < 4; hh++) vf[hh] = vpf[hh];

        if (c + 8 <= ti) {
            const int sn = (c + 8) * 32;
            for (int st2 = 0; st2 < 2; st2++)
                for (int kk = 0; kk < 2; kk++)
                    qpf[st2][kk] = *(const bf16x8*)(qb + (sn + st2 * 16 + l15) * HEAD + kk * 32 + q4 * 8);
            for (int hh = 0; hh < 4; hh++)
                vpf[hh] = *(const bf16x8*)(vtb + (hh * 16 + l15) * (long)TSEQ + sn + q4 * 8);
        }

        // S^T = Q K^T: 2 s-tiles x 2 t-tiles
        f32x4 sc[2][2];
        for (int st2 = 0; st2 < 2; st2++)
            for (int tt = 0; tt < 2; tt++) {
                f32x4 s = z;
                s = __builtin_amdgcn_mfma_f32_16x16x32_bf16(qf[st2][0], kf[tt][0], s, 0, 0, 0);
                s = __builtin_amdgcn_mfma_f32_16x16x32_bf16(qf[st2][1], kf[tt][1], s, 0, 0, 0);
                sc[st2][tt] = s;
            }
        // softplus + causal mask; pack bf16 -> P^T LDS [t-local][s-local]
        for (int tt = 0; tt < 2; tt++) {
            const int tg = t0 + tt * 16 + l15;
            for (int st2 = 0; st2 < 2; st2++) {
                ushort4 pk;
                unsigned short pv[4];
                for (int r = 0; r < 4; r++) {
                    int sg = s0 + st2 * 16 + q4 * 4 + r;
                    float p = __logf(1.0f + __expf(sc[st2][tt][r]));
                    if (sg > tg) p = 0.0f;
                    pv[r] = f2bf(p);
                }
                pk.x = pv[0]; pk.y = pv[1]; pk.z = pv[2]; pk.w = pv[3];
                *(ushort4*)(myP + (tt * 16 + l15) * 40 + st2 * 16 + q4 * 4) = pk;
            }
        }
        __threadfence_block();
        bf16x8 pf0 = *(const bf16x8*)(myP + l15 * 40 + q4 * 8);
        bf16x8 pf1 = *(const bf16x8*)(myP + (16 + l15) * 40 + q4 * 8);
        for (int hh = 0; hh < 4; hh++) {
            oacc[hh][0] = __builtin_amdgcn_mfma_f32_16x16x32_bf16(vf[hh], pf0, oacc[hh][0], 0, 0, 0);
            oacc[hh][1] = __builtin_amdgcn_mfma_f32_16x16x32_bf16(vf[hh], pf1, oacc[hh][1], 0, 0, 0);
        }
    }

    // ---- 3-stage tree reduction over 8 waves (red unions Pl; synced) ----
    __syncthreads();                           // all Pl use done
    if (w >= 4) {
        float* r0 = red + (w - 4) * 2304 + lane * 36;
        for (int hh = 0; hh < 4; hh++)
            for (int tt = 0; tt < 2; tt++)
                *(f32x4*)(r0 + (hh * 2 + tt) * 4) = oacc[hh][tt];
    }
    __syncthreads();
    if (w < 4) {
        const float* r0 = red + w * 2304 + lane * 36;
        for (int hh = 0; hh < 4; hh++)
            for (int tt = 0; tt < 2; tt++)
                oacc[hh][tt] += *(const f32x4*)(r0 + (hh * 2 + tt) * 4);
    }
    __syncthreads();
    if (w == 2 || w == 3) {
        float* r0 = red + (w - 2) * 2304 + lane * 36;
        for (int hh = 0; hh < 4; hh++)
            for (int tt = 0; tt < 2; tt++)
                *(f32x4*)(r0 + (hh * 2 + tt) * 4) = oacc[hh][tt];
    }
    __syncthreads();
    if (w < 2) {
        const float* r0 = red + w * 2304 + lane * 36;
        for (int hh = 0; hh < 4; hh++)
            for (int tt = 0; tt < 2; tt++)
                oacc[hh][tt] += *(const f32x4*)(r0 + (hh * 2 + tt) * 4);
    }
    __syncthreads();
    if (w == 1) {
        float* r0 = red + lane * 36;
        for (int hh = 0; hh < 4; hh++)
            for (int tt = 0; tt < 2; tt++)
                *(f32x4*)(r0 + (hh * 2 + tt) * 4) = oacc[hh][tt];
    }
    __syncthreads();
    if (w == 0) {
        const float* r0 = red + lane * 36;
        for (int hh = 0; hh < 4; hh++)
            for (int tt = 0; tt < 2; tt++)
                oacc[hh][tt] += *(const f32x4*)(r0 + (hh * 2 + tt) * 4);
        for (int tt = 0; tt < 2; tt++) {
            float* ob = out + ((long)b * TSEQ + t0 + tt * 16 + l15) * HEAD + q4 * 4;
            for (int hh = 0; hh < 4; hh++)
                *(f32x4*)(ob + hh * 16) = oacc[hh][tt];
        }
    }
}

// ---------------- host launch ------------------------------------------------
extern "C" void kernel_launch(void* const* d_in, const int* in_sizes, int n_in,
                              void* d_out, int out_size, void* d_ws, size_t ws_size,
                              hipStream_t stream) {
    const float* x  = (const float*)d_in[0];
    const float* Wk = (const float*)d_in[1];
    const float* bk = (const float*)d_in[2];
    const float* Wq = (const float*)d_in[3];
    const float* bq = (const float*)d_in[4];
    const float* Wv = (const float*)d_in[5];
    const float* bv = (const float*)d_in[6];
    float* out = (float*)d_out;

    char* ws = (char*)d_ws;
    unsigned short* WTf   = (unsigned short*)(ws);                      // 384 KB
    float*          biasb = (float*)(ws + 393216);                      // 768 B
    unsigned short* Kb    = (unsigned short*)(ws + 524288);             // 2 MB
    unsigned short* Qb    = (unsigned short*)(ws + 524288 + 2097152);   // 2 MB
    unsigned short* VTb   = (unsigned short*)(ws + 524288 + 4194304);   // 2 MB

    prep_w<<<32, 256, 0, stream>>>(Wk, bk, Wq, bq, Wv, bv, WTf, biasb);
    proj_gemm<<<256, 768, 0, stream>>>(x, WTf, biasb, Kb, Qb, VTb);
    attn<<<512, 512, 0, stream>>>(Kb, Qb, VTb, out);
}

// Round 9
// 153.377 us; speedup vs baseline: 2.2929x; 1.1622x over previous
//
#include <hip/hip_runtime.h>
#include <hip/hip_bf16.h>
#include <stdint.h>

#define HEAD 64
#define CEMB 1024
#define BB 8
#define TSEQ 2048

typedef __attribute__((ext_vector_type(8))) short bf16x8;
typedef __attribute__((ext_vector_type(4))) float f32x4;

__device__ __forceinline__ unsigned short f2bf(float f) {
    union { float f; uint32_t u; } c; c.f = f;
    uint32_t u = c.u + 0x7FFF + ((c.u >> 16) & 1);
    return (unsigned short)(u >> 16);
}
__device__ __forceinline__ ushort4 f4bf(float4 v) {
    ushort4 u; u.x = f2bf(v.x); u.y = f2bf(v.y); u.z = f2bf(v.z); u.w = f2bf(v.w);
    return u;
}

// ---------------- Kernel 0: W -> WTf, MFMA-fragment order --------------------
// Fragment (kc, j): 64 lanes x 16B contiguous (1 KB); n = j*16+(lane&15),
// k = kc*32 + (lane>>4)*8 + e.  j: 0-3 K, 4-7 Q(scaled), 8-11 V.
__global__ __launch_bounds__(256) void prep_w(
        const float* __restrict__ Wk, const float* __restrict__ bk,
        const float* __restrict__ Wq, const float* __restrict__ bq,
        const float* __restrict__ Wv, const float* __restrict__ bv,
        unsigned short* __restrict__ WTf, float* __restrict__ biasb) {
    __shared__ float Wl[3][32][64];
    const int kc = blockIdx.x;               // 0..31
    const int tid = threadIdx.x;
    const float* Ws[3] = {Wk, Wq, Wv};
    const int row = tid >> 3, cf = (tid & 7) * 8;
    #pragma unroll
    for (int p = 0; p < 3; p++) {
        const float* W = Ws[p] + (long)(kc * 32 + row) * 64 + cf;
        float4 v0 = *(const float4*)(W);
        float4 v1 = *(const float4*)(W + 4);
        *(float4*)(&Wl[p][row][cf]) = v0;
        *(float4*)(&Wl[p][row][cf + 4]) = v1;
    }
    __syncthreads();
    #pragma unroll
    for (int i = 0; i < 3; i++) {
        int cid = i * 256 + tid;             // 0..767 = j*64 + lane
        int lane = cid & 63;
        int l15 = lane & 15, q4 = lane >> 4;
        int n = (cid >> 6) * 16 + l15;
        int p = n >> 6, col = n & 63;
        float scale = (p == 1) ? 0.03125f : 1.0f;   // fold C^-0.5 into q
        unsigned short o[8];
        for (int e = 0; e < 8; e++) o[e] = f2bf(Wl[p][q4 * 8 + e][col] * scale);
        *(int4*)(WTf + (long)kc * 6144 + (long)cid * 8) = *(int4*)o;
    }
    if (kc == 0 && tid < 192) {
        const float* bs[3] = {bk, bq, bv};
        int p = tid >> 6;
        biasb[tid] = bs[p][tid & 63] * ((p == 1) ? 0.03125f : 1.0f);
    }
}

// ---------------- Kernel 1: projections, register-B, 2 blocks/CU -------------
// grid 512 x 384thr (6 waves). Block = 32 rows; wave owns 2 n-tiles with
// Breg[2][8] (64 VGPRs, quarter-K, each fragment read once per block).
// (384,3) -> 12 waves/CU as TWO independent blocks: one block computes while
// the other sits in its barrier drain (R8's 1-block/CU exposed every drain).
__global__ __launch_bounds__(384, 3) void proj_gemm(
        const float* __restrict__ x, const unsigned short* __restrict__ WTf,
        const float* __restrict__ biasb,
        unsigned short* __restrict__ Kb, unsigned short* __restrict__ Qb,
        unsigned short* __restrict__ VTb) {
    __shared__ __align__(16) unsigned short As[32 * 1032];   // 66 KB

    const int tid = threadIdx.x;
    const int lane = tid & 63, w = tid >> 6;     // w = 0..5, owns n-tiles 2w,2w+1
    const int l15 = lane & 15, q4 = lane >> 4;
    const long rowbase = (long)blockIdx.x * 32;
    const float* xg = x + rowbase * CEMB;

    f32x4 z = {0.f, 0.f, 0.f, 0.f};
    f32x4 acc[2][2];                             // [n-tile][m-tile]
    for (int nt = 0; nt < 2; nt++) for (int m = 0; m < 2; m++) acc[nt][m] = z;

    bf16x8 Breg[2][8];

    // ---- stage segment 0 (32 rows x k[0:128]) ----
    #pragma unroll
    for (int it = 0; it < 3; it++) {
        int i = it * 384 + tid;
        if (i < 1024) {
            int row = i >> 5, c4 = (i & 31) * 4;
            float4 v = *(const float4*)(xg + row * CEMB + c4);
            *(ushort4*)(As + row * 1032 + c4) = f4bf(v);
        }
    }
    __syncthreads();

    // ---- pipelined K-loop: 4 quarters x 2 segments ----
    #pragma unroll
    for (int qtr = 0; qtr < 4; qtr++) {
        // this quarter's B-fragments for both owned n-tiles (coalesced 1KB, L2-hot)
        #pragma unroll
        for (int nt = 0; nt < 2; nt++)
            #pragma unroll
            for (int i = 0; i < 8; i++)
                Breg[nt][i] = *(const bf16x8*)(
                    WTf + (long)(qtr * 8 + i) * 6144 + (2 * w + nt) * 512 + lane * 8);

        #pragma unroll
        for (int ss = 0; ss < 2; ss++) {
            const int s = qtr * 2 + ss;
            float4 pf[3];
            // issue seg s+1 global loads (in flight across MFMA below)
            if (s < 7) {
                #pragma unroll
                for (int it = 0; it < 3; it++) {
                    int i = it * 384 + tid;
                    if (i < 1024) {
                        int row = i >> 5, c4 = (i & 31) * 4;
                        pf[it] = *(const float4*)(xg + row * CEMB + (s + 1) * 128 + c4);
                    }
                }
            }
            // compute seg s: 4 kc x 2 m x 2 n-tiles, B from registers
            #pragma unroll
            for (int kc = 0; kc < 4; kc++) {
                const int kg = s * 4 + kc;
                #pragma unroll
                for (int m = 0; m < 2; m++) {
                    bf16x8 a = *(const bf16x8*)(As + (m * 16 + l15) * 1032 + kg * 32 + q4 * 8);
                    #pragma unroll
                    for (int nt = 0; nt < 2; nt++)
                        acc[nt][m] = __builtin_amdgcn_mfma_f32_16x16x32_bf16(
                            a, Breg[nt][ss * 4 + kc], acc[nt][m], 0, 0, 0);
                }
            }
            // store seg s+1 (disjoint LDS columns), then barrier
            if (s < 7) {
                #pragma unroll
                for (int it = 0; it < 3; it++) {
                    int i = it * 384 + tid;
                    if (i < 1024) {
                        int row = i >> 5, c4 = (i & 31) * 4;
                        *(ushort4*)(As + row * 1032 + (s + 1) * 128 + c4) = f4bf(pf[it]);
                    }
                }
                __syncthreads();
            }
        }
    }

    // ---- epilogue: +bias, cast bf16, per-wave scatter ----
    #pragma unroll
    for (int nt = 0; nt < 2; nt++) {
        const int n = (2 * w + nt) * 16 + l15;
        const float bias = biasb[n];
        #pragma unroll
        for (int m = 0; m < 2; m++) {
            const long row0 = rowbase + m * 16 + q4 * 4;
            if (n < 128) {
                unsigned short* dst = (n < 64) ? (Kb + row0 * HEAD + n)
                                               : (Qb + row0 * HEAD + (n - 64));
                for (int r = 0; r < 4; r++)
                    dst[r * HEAD] = f2bf(acc[nt][m][r] + bias);
            } else {
                const int h = n - 128;
                const long b = row0 >> 11; const int t = (int)(row0 & 2047);
                ushort4 pk;
                pk.x = f2bf(acc[nt][m][0] + bias);
                pk.y = f2bf(acc[nt][m][1] + bias);
                pk.z = f2bf(acc[nt][m][2] + bias);
                pk.w = f2bf(acc[nt][m][3] + bias);
                *(ushort4*)(VTb + b * (HEAD * (long)TSEQ) + (long)h * TSEQ + t) = pk;
            }
        }
    }
}

// ---------------- Kernel 2: causal softplus-attention (R6 verbatim) ----------
// Default launch bounds: R8's (512,4) capped VGPR at 128 and spilled ~80 MB
// of scratch traffic (WRITE_SIZE 47.6 MB vs 4 MB output). R6 config was fine.
__global__ __launch_bounds__(512) void attn(
        const unsigned short* __restrict__ Kb, const unsigned short* __restrict__ Qb,
        const unsigned short* __restrict__ VTb, float* __restrict__ out) {
    __shared__ __align__(16) char sm[36864];   // union: Pl 20480 | red 36864
    unsigned short* Pl = (unsigned short*)sm;  // [8 waves][32*40]
    float* red = (float*)sm;                   // [4][64*36]

    const int tid = threadIdx.x;
    const int lane = tid & 63, w = tid >> 6;   // 8 waves
    const int l15 = lane & 15, q4 = lane >> 4;

    const int bid = blockIdx.x;
    const int ti = 63 - (bid >> 3);            // largest t-tile first
    const int b = bid & 7;
    const int t0 = ti * 32;

    const unsigned short* kb  = Kb  + (long)b * TSEQ * HEAD;
    const unsigned short* qb  = Qb  + (long)b * TSEQ * HEAD;
    const unsigned short* vtb = VTb + (long)b * HEAD * TSEQ;

    bf16x8 kf[2][2];
    for (int tt = 0; tt < 2; tt++)
        for (int kk = 0; kk < 2; kk++)
            kf[tt][kk] = *(const bf16x8*)(kb + (t0 + tt * 16 + l15) * HEAD + kk * 32 + q4 * 8);

    f32x4 z = {0.f, 0.f, 0.f, 0.f};
    f32x4 oacc[4][2];
    for (int hh = 0; hh < 4; hh++) for (int tt = 0; tt < 2; tt++) oacc[hh][tt] = z;

    bf16x8 qpf[2][2], vpf[4];
    if (w <= ti) {
        const int s0 = w * 32;
        for (int st2 = 0; st2 < 2; st2++)
            for (int kk = 0; kk < 2; kk++)
                qpf[st2][kk] = *(const bf16x8*)(qb + (s0 + st2 * 16 + l15) * HEAD + kk * 32 + q4 * 8);
        for (int hh = 0; hh < 4; hh++)
            vpf[hh] = *(const bf16x8*)(vtb + (hh * 16 + l15) * (long)TSEQ + s0 + q4 * 8);
    }

    unsigned short* myP = Pl + w * 1280;
    for (int c = w; c <= ti; c += 8) {
        const int s0 = c * 32;

        bf16x8 qf[2][2], vf[4];
        for (int st2 = 0; st2 < 2; st2++)
            for (int kk = 0; kk < 2; kk++) qf[st2][kk] = qpf[st2][kk];
        for (int hh = 0; hh < 4; hh++) vf[hh] = vpf[hh];

        if (c + 8 <= ti) {
            const int sn = (c + 8) * 32;
            for (int st2 = 0; st2 < 2; st2++)
                for (int kk = 0; kk < 2; kk++)
                    qpf[st2][kk] = *(const bf16x8*)(qb + (sn + st2 * 16 + l15) * HEAD + kk * 32 + q4 * 8);
            for (int hh = 0; hh < 4; hh++)
                vpf[hh] = *(const bf16x8*)(vtb + (hh * 16 + l15) * (long)TSEQ + sn + q4 * 8);
        }

        // S^T = Q K^T: 2 s-tiles x 2 t-tiles
        f32x4 sc[2][2];
        for (int st2 = 0; st2 < 2; st2++)
            for (int tt = 0; tt < 2; tt++) {
                f32x4 s = z;
                s = __builtin_amdgcn_mfma_f32_16x16x32_bf16(qf[st2][0], kf[tt][0], s, 0, 0, 0);
                s = __builtin_amdgcn_mfma_f32_16x16x32_bf16(qf[st2][1], kf[tt][1], s, 0, 0, 0);
                sc[st2][tt] = s;
            }
        // softplus + causal mask; pack bf16 -> P^T LDS [t-local][s-local]
        for (int tt = 0; tt < 2; tt++) {
            const int tg = t0 + tt * 16 + l15;
            for (int st2 = 0; st2 < 2; st2++) {
                ushort4 pk;
                unsigned short pv[4];
                for (int r = 0; r < 4; r++) {
                    int sg = s0 + st2 * 16 + q4 * 4 + r;
                    float p = __logf(1.0f + __expf(sc[st2][tt][r]));
                    if (sg > tg) p = 0.0f;
                    pv[r] = f2bf(p);
                }
                pk.x = pv[0]; pk.y = pv[1]; pk.z = pv[2]; pk.w = pv[3];
                *(ushort4*)(myP + (tt * 16 + l15) * 40 + st2 * 16 + q4 * 4) = pk;
            }
        }
        __threadfence_block();
        bf16x8 pf0 = *(const bf16x8*)(myP + l15 * 40 + q4 * 8);
        bf16x8 pf1 = *(const bf16x8*)(myP + (16 + l15) * 40 + q4 * 8);
        for (int hh = 0; hh < 4; hh++) {
            oacc[hh][0] = __builtin_amdgcn_mfma_f32_16x16x32_bf16(vf[hh], pf0, oacc[hh][0], 0, 0, 0);
            oacc[hh][1] = __builtin_amdgcn_mfma_f32_16x16x32_bf16(vf[hh], pf1, oacc[hh][1], 0, 0, 0);
        }
    }

    // ---- 3-stage tree reduction over 8 waves (red unions Pl; synced) ----
    __syncthreads();                           // all Pl use done
    if (w >= 4) {
        float* r0 = red + (w - 4) * 2304 + lane * 36;
        for (int hh = 0; hh < 4; hh++)
            for (int tt = 0; tt < 2; tt++)
                *(f32x4*)(r0 + (hh * 2 + tt) * 4) = oacc[hh][tt];
    }
    __syncthreads();
    if (w < 4) {
        const float* r0 = red + w * 2304 + lane * 36;
        for (int hh = 0; hh < 4; hh++)
            for (int tt = 0; tt < 2; tt++)
                oacc[hh][tt] += *(const f32x4*)(r0 + (hh * 2 + tt) * 4);
    }
    __syncthreads();
    if (w == 2 || w == 3) {
        float* r0 = red + (w - 2) * 2304 + lane * 36;
        for (int hh = 0; hh < 4; hh++)
            for (int tt = 0; tt < 2; tt++)
                *(f32x4*)(r0 + (hh * 2 + tt) * 4) = oacc[hh][tt];
    }
    __syncthreads();
    if (w < 2) {
        const float* r0 = red + w * 2304 + lane * 36;
        for (int hh = 0; hh < 4; hh++)
            for (int tt = 0; tt < 2; tt++)
                oacc[hh][tt] += *(const f32x4*)(r0 + (hh * 2 + tt) * 4);
    }
    __syncthreads();
    if (w == 1) {
        float* r0 = red + lane * 36;
        for (int hh = 0; hh < 4; hh++)
            for (int tt = 0; tt < 2; tt++)
                *(f32x4*)(r0 + (hh * 2 + tt) * 4) = oacc[hh][tt];
    }
    __syncthreads();
    if (w == 0) {
        const float* r0 = red + lane * 36;
        for (int hh = 0; hh < 4; hh++)
            for (int tt = 0; tt < 2; tt++)
                oacc[hh][tt] += *(const f32x4*)(r0 + (hh * 2 + tt) * 4);
        for (int tt = 0; tt < 2; tt++) {
            float* ob = out + ((long)b * TSEQ + t0 + tt * 16 + l15) * HEAD + q4 * 4;
            for (int hh = 0; hh < 4; hh++)
                *(f32x4*)(ob + hh * 16) = oacc[hh][tt];
        }
    }
}

// ---------------- host launch ------------------------------------------------
extern "C" void kernel_launch(void* const* d_in, const int* in_sizes, int n_in,
                              void* d_out, int out_size, void* d_ws, size_t ws_size,
                              hipStream_t stream) {
    const float* x  = (const float*)d_in[0];
    const float* Wk = (const float*)d_in[1];
    const float* bk = (const float*)d_in[2];
    const float* Wq = (const float*)d_in[3];
    const float* bq = (const float*)d_in[4];
    const float* Wv = (const float*)d_in[5];
    const float* bv = (const float*)d_in[6];
    float* out = (float*)d_out;

    char* ws = (char*)d_ws;
    unsigned short* WTf   = (unsigned short*)(ws);                      // 384 KB
    float*          biasb = (float*)(ws + 393216);                      // 768 B
    unsigned short* Kb    = (unsigned short*)(ws + 524288);             // 2 MB
    unsigned short* Qb    = (unsigned short*)(ws + 524288 + 2097152);   // 2 MB
    unsigned short* VTb   = (unsigned short*)(ws + 524288 + 4194304);   // 2 MB

    prep_w<<<32, 256, 0, stream>>>(Wk, bk, Wq, bq, Wv, bv, WTf, biasb);
    proj_gemm<<<512, 384, 0, stream>>>(x, WTf, biasb, Kb, Qb, VTb);
    attn<<<512, 512, 0, stream>>>(Kb, Qb, VTb, out);
}